// Round 1
// baseline (203.451 us; speedup 1.0000x reference)
//
#include <hip/hip_runtime.h>

// Connected components via GPU union-find (atomicMin), replacing the
// reference's iterated 3x3 max-pool fixed point.
//
// Label semantics: weights[l] = MULT - l for local linear index l in [0,MULT);
// fixed point assigns each fg pixel max weight over its 8-connected component
// = MULT - min(local index). Background -> 0.

constexpr int W_DIM = 2048;
constexpr int LOGW  = 11;                  // W_DIM = 2^11
constexpr int MULT  = W_DIM * W_DIM;       // 2^22 per-image pixel count
constexpr int BLK   = 256;

__device__ __forceinline__ int find_root(const int* __restrict__ parent, int v) {
    int p = parent[v];
    while (p != v) { v = p; p = parent[v]; }
    return v;
}

// Playne-Hawick style concurrent union: link larger root under smaller via
// atomicMin; retry with the displaced value on contention. parent[p] <= p is
// an invariant, so all walks terminate; every stored value is a true ancestor,
// so stale (non-atomic) reads are still safe.
__device__ __forceinline__ void merge_uf(int* parent, int a, int b) {
    while (true) {
        a = find_root(parent, a);
        b = find_root(parent, b);
        if (a == b) return;
        if (a < b) { int t = a; a = b; b = t; }   // ensure a > b
        int old = atomicMin(&parent[a], b);
        if (old == a) return;                     // a was root; linked under b
        a = old;                                  // someone else linked a; retry
    }
}

__global__ void cc_init(int* __restrict__ parent, int n4) {
    int i = blockIdx.x * blockDim.x + threadIdx.x;
    if (i >= n4) return;
    int b = i * 4;
    reinterpret_cast<int4*>(parent)[i] = make_int4(b, b + 1, b + 2, b + 3);
}

__global__ void cc_merge(const float* __restrict__ x, int* __restrict__ parent, int n) {
    int i = blockIdx.x * blockDim.x + threadIdx.x;
    if (i >= n) return;
    if (x[i] == 0.0f) return;                    // background: nothing to do
    int l   = i & (MULT - 1);                    // local index within image
    int col = l & (W_DIM - 1);
    int row = l >> LOGW;

    bool lf = (col > 0) && (x[i - 1] != 0.0f);   // left
    if (lf) merge_uf(parent, i, i - 1);

    if (row > 0) {
        bool bf = (x[i - W_DIM] != 0.0f);                          // up
        bool af = (col > 0)         && (x[i - W_DIM - 1] != 0.0f); // up-left
        bool cf = (col < W_DIM - 1) && (x[i - W_DIM + 1] != 0.0f); // up-right
        // Redundant-edge suppression (each skipped edge is covered by a
        // neighbor's own left/up merge):
        if (bf && !(af && lf)) merge_uf(parent, i, i - W_DIM);
        if (af && !bf && !lf)  merge_uf(parent, i, i - W_DIM - 1);
        if (cf && !bf)         merge_uf(parent, i, i - W_DIM + 1);
    }
}

// Full path compression so that parent[i] == root for every pixel.
// Write only when the value changes (most pixels are their own root).
__global__ void cc_flatten(int* __restrict__ parent, int n) {
    int i = blockIdx.x * blockDim.x + threadIdx.x;
    if (i >= n) return;
    int p = parent[i];
    if (p == i) return;
    int r = find_root(parent, p);
    if (r != p) parent[i] = r;
}

// In-place relabel (parent aliases d_out): after cc_flatten each thread reads
// ONLY its own element, so overwriting ints with floats is race-free.
__global__ void cc_relabel_inplace(const float* __restrict__ x, int* __restrict__ parent, int n4) {
    int i = blockIdx.x * blockDim.x + threadIdx.x;
    if (i >= n4) return;
    float4 xv = reinterpret_cast<const float4*>(x)[i];
    int4   p  = reinterpret_cast<const int4*>(parent)[i];
    float4 o;
    o.x = (xv.x != 0.0f) ? (float)(MULT - (p.x & (MULT - 1))) : 0.0f;
    o.y = (xv.y != 0.0f) ? (float)(MULT - (p.y & (MULT - 1))) : 0.0f;
    o.z = (xv.z != 0.0f) ? (float)(MULT - (p.z & (MULT - 1))) : 0.0f;
    o.w = (xv.w != 0.0f) ? (float)(MULT - (p.w & (MULT - 1))) : 0.0f;
    reinterpret_cast<float4*>(parent)[i] = o;
}

// Workspace path: parent lives in d_ws, walk chains directly and write d_out.
__global__ void cc_relabel_walk(const float* __restrict__ x, const int* __restrict__ parent,
                                float* __restrict__ out, int n4) {
    int i = blockIdx.x * blockDim.x + threadIdx.x;
    if (i >= n4) return;
    float4 xv = reinterpret_cast<const float4*>(x)[i];
    int base = i * 4;
    float4 o;
    o.x = (xv.x != 0.0f) ? (float)(MULT - (find_root(parent, base + 0) & (MULT - 1))) : 0.0f;
    o.y = (xv.y != 0.0f) ? (float)(MULT - (find_root(parent, base + 1) & (MULT - 1))) : 0.0f;
    o.z = (xv.z != 0.0f) ? (float)(MULT - (find_root(parent, base + 2) & (MULT - 1))) : 0.0f;
    o.w = (xv.w != 0.0f) ? (float)(MULT - (find_root(parent, base + 3) & (MULT - 1))) : 0.0f;
    reinterpret_cast<float4*>(out)[i] = o;
}

extern "C" void kernel_launch(void* const* d_in, const int* in_sizes, int n_in,
                              void* d_out, int out_size, void* d_ws, size_t ws_size,
                              hipStream_t stream) {
    const float* x = (const float*)d_in[0];
    const int n  = in_sizes[0];      // B*H*W = 16,777,216
    const int n4 = n / 4;

    const bool use_ws = (ws_size >= (size_t)n * sizeof(int));
    int* parent = use_ws ? (int*)d_ws : (int*)d_out;

    dim3 blk(BLK);
    dim3 grid_n((n  + BLK - 1) / BLK);
    dim3 grid_4((n4 + BLK - 1) / BLK);

    cc_init <<<grid_4, blk, 0, stream>>>(parent, n4);
    cc_merge<<<grid_n, blk, 0, stream>>>(x, parent, n);
    if (use_ws) {
        cc_relabel_walk<<<grid_4, blk, 0, stream>>>(x, parent, (float*)d_out, n4);
    } else {
        cc_flatten        <<<grid_n, blk, 0, stream>>>(parent, n);
        cc_relabel_inplace<<<grid_4, blk, 0, stream>>>(x, parent, n4);
    }
}

// Round 2
// 93.838 us; speedup vs baseline: 2.1681x; 2.1681x over previous
//
#include <hip/hip_runtime.h>

// Two-level connected components (block-local union-find in LDS, then
// global border merges), replacing the single-level global union-find.
//
// Label semantics: out = MULT - min(local linear index over 8-conn component)
// for foreground, 0 for background.
//
// parent[] encoding: -1 = background (never read/written by merges),
// >=0 = union-find parent (global pixel index). parent[p] <= p invariant
// guarantees termination; every stored value is a true ancestor, so stale
// non-atomic reads remain safe (proved in round 1).

constexpr int W_DIM = 2048;
constexpr int H_DIM = 2048;
constexpr int MULT  = W_DIM * H_DIM;        // 2^22 pixels per image
constexpr int TILE  = 64;
constexpr int TPX   = TILE * TILE;          // 4096 pixels per tile
constexpr int BLK   = 256;
constexpr int TILES_PER_IMG = MULT / TPX;   // 1024
constexpr int NB    = (H_DIM / TILE) - 1;   // 31 interior boundaries per dim

__device__ __forceinline__ int find_root(const int* p, int v) {
    int q = p[v];
    while (q != v) { v = q; q = p[v]; }
    return v;
}

// atomicMin-based concurrent union; works identically on LDS and global.
__device__ __forceinline__ void merge_uf(int* p, int a, int b) {
    while (true) {
        a = find_root(p, a);
        b = find_root(p, b);
        if (a == b) return;
        if (a < b) { int t = a; a = b; b = t; }  // a > b
        int old = atomicMin(&p[a], b);
        if (old == a) return;                    // a was root; linked under b
        a = old;                                 // displaced; retry from old
    }
}

// Phase 1: per-tile local CCL in LDS; write global parent (bg = -1).
__global__ __launch_bounds__(BLK) void cc_local(const float* __restrict__ x,
                                                int* __restrict__ parent) {
    __shared__ int lp[TPX];
    const int t    = threadIdx.x;
    const int tile = blockIdx.x;
    const int img  = tile / TILES_PER_IMG;
    const int tl   = tile % TILES_PER_IMG;
    const int tr   = tl >> 5;                // 32 tile cols per image row
    const int tc   = tl & 31;
    const int origin = img * MULT + (tr * TILE) * W_DIM + tc * TILE;

    // init: coalesced float4 loads of x; lp[p] = p (fg) or -1 (bg)
    #pragma unroll
    for (int j = 0; j < 4; ++j) {
        int s   = t + BLK * j;               // float4 slot in tile
        int row = s >> 4;                    // 16 slots per 64-px row
        int c4  = s & 15;
        float4 xv = reinterpret_cast<const float4*>(x + origin + row * W_DIM)[c4];
        int p0 = row * TILE + c4 * 4;
        int4 v;
        v.x = (xv.x != 0.f) ? p0     : -1;
        v.y = (xv.y != 0.f) ? p0 + 1 : -1;
        v.z = (xv.z != 0.f) ? p0 + 2 : -1;
        v.w = (xv.w != 0.f) ? p0 + 3 : -1;
        reinterpret_cast<int4*>(lp)[s] = v;
    }
    __syncthreads();

    // merge: left/up/up-left/up-right within tile (LDS atomics).
    // Suppression set is tile-closed: every skipped edge's covering edges
    // also lie within the tile.
    #pragma unroll
    for (int j = 0; j < 4; ++j) {
        int s  = t + BLK * j;
        int p0 = (s >> 4) * TILE + (s & 15) * 4;
        #pragma unroll
        for (int k = 0; k < 4; ++k) {
            int p = p0 + k;
            if (lp[p] < 0) continue;
            int lc = p & (TILE - 1);
            bool lf = (lc > 0) && (lp[p - 1] >= 0);
            if (lf) merge_uf(lp, p, p - 1);
            if (p >= TILE) {
                bool bf = lp[p - TILE] >= 0;
                bool af = (lc > 0)        && (lp[p - TILE - 1] >= 0);
                bool cf = (lc < TILE - 1) && (lp[p - TILE + 1] >= 0);
                if (bf && !(af && lf)) merge_uf(lp, p, p - TILE);
                if (af && !bf && !lf)  merge_uf(lp, p, p - TILE - 1);
                if (cf && !bf)         merge_uf(lp, p, p - TILE + 1);
            }
        }
    }
    __syncthreads();

    // flatten to local root, convert to global index, stream out.
    #pragma unroll
    for (int j = 0; j < 4; ++j) {
        int s   = t + BLK * j;
        int row = s >> 4;
        int c4  = s & 15;
        int p0  = row * TILE + c4 * 4;
        int g[4];
        #pragma unroll
        for (int k = 0; k < 4; ++k) {
            int p = p0 + k;
            if (lp[p] < 0) { g[k] = -1; continue; }
            int r = find_root(lp, p);
            g[k] = origin + (r >> 6) * W_DIM + (r & (TILE - 1));
        }
        int4 o = make_int4(g[0], g[1], g[2], g[3]);
        reinterpret_cast<int4*>(parent + origin + row * W_DIM)[c4] = o;
    }
}

// Phase 2: merge edges that cross tile boundaries (global atomics, rare).
__global__ __launch_bounds__(BLK) void cc_border(int* __restrict__ parent, int total) {
    int tid = blockIdx.x * blockDim.x + threadIdx.x;
    if (tid >= total) return;
    const int per_img = 2 * NB * W_DIM;
    int img = tid / per_img;
    int k   = tid % per_img;
    int base = img * MULT;
    if (k < NB * W_DIM) {
        // horizontal tile boundary: row r (r % 64 == 0), edges to row r-1
        int r = TILE * (1 + k / W_DIM);
        int c = k % W_DIM;
        int i = base + r * W_DIM + c;
        if (parent[i] < 0) return;
        int up = i - W_DIM;
        if (parent[up] >= 0)                      merge_uf(parent, i, up);
        if (c > 0         && parent[up - 1] >= 0) merge_uf(parent, i, up - 1);
        if (c < W_DIM - 1 && parent[up + 1] >= 0) merge_uf(parent, i, up + 1);
    } else {
        // vertical tile boundary: col c (c % 64 == 0), edges to col c-1
        int m = k - NB * W_DIM;
        int c = TILE * (1 + m / H_DIM);
        int r = m % H_DIM;
        int i = base + r * W_DIM + c;
        if (parent[i] < 0) return;
        int lft = i - 1;
        if (parent[lft] >= 0)                            merge_uf(parent, i, lft);
        if (r > 0         && parent[lft - W_DIM] >= 0)   merge_uf(parent, i, lft - W_DIM);
        if (r < H_DIM - 1 && parent[lft + W_DIM] >= 0)   merge_uf(parent, i, lft + W_DIM);
    }
}

// Phase 3 (workspace path): walk to root, write labels. fg flag rides in parent.
__global__ __launch_bounds__(BLK) void cc_write(const int* __restrict__ parent,
                                                float* __restrict__ out, int n4) {
    int i = blockIdx.x * blockDim.x + threadIdx.x;
    if (i >= n4) return;
    int4 p = reinterpret_cast<const int4*>(parent)[i];
    float4 o;
    o.x = (p.x < 0) ? 0.f : (float)(MULT - (find_root(parent, p.x) & (MULT - 1)));
    o.y = (p.y < 0) ? 0.f : (float)(MULT - (find_root(parent, p.y) & (MULT - 1)));
    o.z = (p.z < 0) ? 0.f : (float)(MULT - (find_root(parent, p.z) & (MULT - 1)));
    o.w = (p.w < 0) ? 0.f : (float)(MULT - (find_root(parent, p.w) & (MULT - 1)));
    reinterpret_cast<float4*>(out)[i] = o;
}

// No-workspace path: full path compression, then race-free in-place relabel.
__global__ __launch_bounds__(BLK) void cc_flatten(int* __restrict__ parent, int n) {
    int i = blockIdx.x * blockDim.x + threadIdx.x;
    if (i >= n) return;
    int p = parent[i];
    if (p < 0 || p == i) return;
    int r = find_root(parent, p);
    if (r != p) parent[i] = r;
}

__global__ __launch_bounds__(BLK) void cc_final_inplace(int* __restrict__ parent, int n4) {
    int i = blockIdx.x * blockDim.x + threadIdx.x;
    if (i >= n4) return;
    int4 p = reinterpret_cast<const int4*>(parent)[i];
    float4 o;
    o.x = (p.x < 0) ? 0.f : (float)(MULT - (p.x & (MULT - 1)));
    o.y = (p.y < 0) ? 0.f : (float)(MULT - (p.y & (MULT - 1)));
    o.z = (p.z < 0) ? 0.f : (float)(MULT - (p.z & (MULT - 1)));
    o.w = (p.w < 0) ? 0.f : (float)(MULT - (p.w & (MULT - 1)));
    reinterpret_cast<float4*>(parent)[i] = o;
}

extern "C" void kernel_launch(void* const* d_in, const int* in_sizes, int n_in,
                              void* d_out, int out_size, void* d_ws, size_t ws_size,
                              hipStream_t stream) {
    const float* x = (const float*)d_in[0];
    const int n     = in_sizes[0];          // B*H*W
    const int n_img = n / MULT;
    const int n4    = n / 4;
    const int tiles = n_img * TILES_PER_IMG;
    const int border_threads = n_img * 2 * NB * W_DIM;

    const bool use_ws = (ws_size >= (size_t)n * sizeof(int));
    int* parent = use_ws ? (int*)d_ws : (int*)d_out;

    dim3 blk(BLK);
    cc_local <<<tiles, blk, 0, stream>>>(x, parent);
    cc_border<<<(border_threads + BLK - 1) / BLK, blk, 0, stream>>>(parent, border_threads);
    if (use_ws) {
        cc_write<<<(n4 + BLK - 1) / BLK, blk, 0, stream>>>(parent, (float*)d_out, n4);
    } else {
        cc_flatten      <<<(n + BLK - 1) / BLK, blk, 0, stream>>>(parent, n);
        cc_final_inplace<<<(n4 + BLK - 1) / BLK, blk, 0, stream>>>(parent, n4);
    }
}